// Round 3
// baseline (118.557 us; speedup 1.0000x reference)
//
#include <hip/hip_runtime.h>
#include <stdint.h>

// DecoderCell, folded algebra + flash-style fused attention.
//   k0: wq[b,h,:] = 0.25 * Wk1[:,h*16:+16] @ (graph@Wqf + ctx@Wqs)[h]
//   kA: per (b, N-slice): online-softmax partials over node rows:
//         m_j, z_j = sum exp(score-m_j), v_j[:] = sum exp(score-m_j)*node[n,:]
//       (one streaming read of node; scores+softmax+weighted-sum fused)
//   kB: combine slice partials -> s[h,:]; mha -> q2 -> w2=(Wk2@q2)/sqrt(128)
//   k5: logit[b,n] = mask ? -1e9 : 10*tanh(node[b,n,:] . w2)   (L3-served pass)

#define DD 128
#define NH 8
#define DHD 16
#define NS 8
#define TILE 64
#define RP 132     // padded row stride (floats): bank-conflict-free float4 rows
#define SP 9       // score row stride: gcd(9,32)=1 -> conflict-free column reads
#define NMAX_PAD 1024

__device__ __forceinline__ bool detect_mask32(const void* maskp) {
    // int32 0/1 mask -> first 16 words all <=1; packed bool8 -> astronomically unlikely
    const uint32_t* mw = (const uint32_t*)maskp;
    bool m32 = true;
    #pragma unroll
    for (int i = 0; i < 16; ++i) m32 = m32 && (mw[i] <= 1u);
    return m32;
}

// ---------------- k0: per-head folded query ----------------
__global__ __launch_bounds__(128)
void k0_prep(const float* __restrict__ graph, const float* __restrict__ ctx,
             const float* __restrict__ Wk1, const float* __restrict__ Wqf,
             const float* __restrict__ Wqs, float* __restrict__ wq_ws)
{
    __shared__ float q1[DD];
    const int b = blockIdx.x, tid = threadIdx.x;
    const float* ge = graph + (size_t)b * DD;
    const float* sc = ctx + (size_t)b * (DD + 2);
    float acc = 0.f;
    #pragma unroll 4
    for (int k = 0; k < DD; ++k)     acc += ge[k] * Wqf[k * DD + tid];
    #pragma unroll 4
    for (int k = 0; k < DD + 2; ++k) acc += sc[k] * Wqs[k * DD + tid];
    q1[tid] = acc;
    __syncthreads();
    const float* wrow = Wk1 + (size_t)tid * DD;   // row dp = tid
    #pragma unroll
    for (int h = 0; h < NH; ++h) {
        float a = 0.f;
        #pragma unroll
        for (int j = 0; j < DHD; ++j) a += wrow[h * DHD + j] * q1[h * DHD + j];
        wq_ws[(size_t)b * NH * DD + h * DD + tid] = 0.25f * a;  // 1/sqrt(16)
    }
}

// ---------------- kA: fused scores + online softmax + weighted sum ----------------
__global__ __launch_bounds__(512)
void kA_flash(const float* __restrict__ node, const float* __restrict__ wq_ws,
              const void* __restrict__ maskp, float* __restrict__ spart_ws,
              float* __restrict__ mz_ws, int N)
{
    __shared__ float tile[TILE * RP];   // 33.8 KB
    __shared__ float wq_l[NH * RP];     // 4.2 KB
    __shared__ float s_t[TILE * SP];    // 2.3 KB  (scores, then exp values)
    const int b = blockIdx.y, j = blockIdx.x, tid = threadIdx.x;
    const int lane = tid & 63, h = tid >> 6;     // wave == head
    const int rows = (N + NS - 1) / NS;
    const int n0 = j * rows;
    const int nend = min(n0 + rows, N);
    const bool m32 = detect_mask32(maskp);
    const int32_t* mi = (const int32_t*)maskp + (size_t)b * N;
    const uint8_t* mb = (const uint8_t*)maskp + (size_t)b * N;
    const float* nodeB = node + (size_t)b * N * DD;

    for (int i = tid; i < NH * DD; i += 512)
        wq_l[(i >> 7) * RP + (i & 127)] = wq_ws[(size_t)b * NH * DD + i];
    // (first tile-load __syncthreads covers wq_l visibility)

    const int r_sc = tid >> 3, h_sc = tid & 7;   // score-phase layout: 64 rows x 8 heads
    float m_run = -1e9f, z_run = 0.f;            // -1e9 == reference's mask sentinel
    float accx = 0.f, accy = 0.f;

    const int ntiles = (nend - n0 + TILE - 1) / TILE;
    for (int t = 0; t < ntiles; ++t) {
        const int nt0 = n0 + t * TILE;
        // -- stage tile (64 x 128, float4-coalesced)
        #pragma unroll
        for (int c = 0; c < 4; ++c) {
            const int idx = c * 2048 + tid * 4;
            const int row = idx >> 7, col = idx & 127;
            if (nt0 + row < nend)
                *(float4*)&tile[row * RP + col] =
                    *(const float4*)(nodeB + (size_t)(nt0 + row) * DD + col);
        }
        __syncthreads();
        // -- scores: thread (r_sc, h_sc)
        {
            const int n = nt0 + r_sc;
            float sc = -1e9f;
            if (n < nend) {
                const bool m = m32 ? (mi[n] != 0) : (mb[n] != 0);
                if (!m) {
                    const float4* nr = (const float4*)&tile[r_sc * RP];
                    const float4* wr = (const float4*)&wq_l[h_sc * RP];
                    float a = 0.f;
                    #pragma unroll
                    for (int k = 0; k < 32; ++k) {
                        const float4 x = nr[k], w = wr[k];
                        a += x.x * w.x + x.y * w.y + x.z * w.z + x.w * w.w;
                    }
                    sc = a;
                }
            }
            s_t[r_sc * SP + h_sc] = sc;
        }
        __syncthreads();
        // -- online softmax update (wave h owns head h; lane == row)
        {
            float scl = s_t[lane * SP + h];
            float tmax = scl;
            #pragma unroll
            for (int d = 1; d < 64; d <<= 1) tmax = fmaxf(tmax, __shfl_xor(tmax, d));
            const float m_new = fmaxf(m_run, tmax);
            const float rescale = __expf(m_run - m_new);
            const float e = __expf(scl - m_new);
            s_t[lane * SP + h] = e;          // intra-wave overwrite, no barrier needed
            float zt = e;
            #pragma unroll
            for (int d = 1; d < 64; d <<= 1) zt += __shfl_xor(zt, d);
            z_run = z_run * rescale + zt;
            accx *= rescale;
            accy *= rescale;
            m_run = m_new;
        }
        // -- weighted accumulate: lane = column pair, broadcast e per row
        #pragma unroll 8
        for (int r = 0; r < TILE; ++r) {
            const float ef = s_t[r * SP + h];
            const float2 v = *(const float2*)&tile[r * RP + 2 * lane];
            accx += ef * v.x;
            accy += ef * v.y;
        }
        __syncthreads();
    }
    // -- write partials
    float* vout = spart_ws + (((size_t)b * NS + j) * NH + h) * DD;
    vout[2 * lane]     = accx;
    vout[2 * lane + 1] = accy;
    if (lane == 0) {
        float* mzp = mz_ws + (((size_t)b * NS + j) * NH + h) * 2;
        mzp[0] = m_run;
        mzp[1] = z_run;
    }
}

// ---------------- kB: combine partials + mha + q2 + w2 ----------------
__global__ __launch_bounds__(128)
void kB_combine(const float* __restrict__ spart_ws, const float* __restrict__ mz_ws,
                const float* __restrict__ Wv, const float* __restrict__ Wout,
                const float* __restrict__ Wk2, float* __restrict__ w2_ws)
{
    __shared__ float m_l[NH * NS], z_l[NH * NS], wt[NH * NS];
    __shared__ float s_l[NH * DD];
    __shared__ float mha_l[DD];
    __shared__ float q2_l[DD];
    const int b = blockIdx.x, tid = threadIdx.x;

    if (tid < NH * NS) {
        const int h = tid >> 3, j = tid & 7;
        const float* mzp = mz_ws + (((size_t)b * NS + j) * NH + h) * 2;
        m_l[h * NS + j] = mzp[0];
        z_l[h * NS + j] = mzp[1];
    }
    __syncthreads();
    if (tid < NH) {
        const int h = tid;
        float M = -1e30f;
        #pragma unroll
        for (int j = 0; j < NS; ++j) M = fmaxf(M, m_l[h * NS + j]);
        float w[NS], Z = 0.f;
        #pragma unroll
        for (int j = 0; j < NS; ++j) {
            w[j] = __expf(m_l[h * NS + j] - M);
            Z += z_l[h * NS + j] * w[j];
        }
        const float rz = 1.f / Z;
        #pragma unroll
        for (int j = 0; j < NS; ++j) wt[h * NS + j] = w[j] * rz;
    }
    __syncthreads();
    const float* sp = spart_ws + (size_t)b * NS * NH * DD;
    for (int o = tid; o < NH * DD; o += 128) {
        const int h = o >> 7;
        float s = 0.f;
        #pragma unroll
        for (int j = 0; j < NS; ++j)
            s += sp[(size_t)j * NH * DD + o] * wt[h * NS + j];
        s_l[o] = s;
    }
    __syncthreads();
    {   // mha[e] = s[h(e)] . Wv[:,e]
        const int h = tid >> 4;
        float a = 0.f;
        for (int dp = 0; dp < DD; ++dp) a += s_l[h * DD + dp] * Wv[dp * DD + tid];
        mha_l[tid] = a;
    }
    __syncthreads();
    {   // q2 = mha @ Wout
        float a = 0.f;
        for (int e = 0; e < DD; ++e) a += mha_l[e] * Wout[e * DD + tid];
        q2_l[tid] = a;
    }
    __syncthreads();
    {   // w2 = (Wk2 @ q2) / sqrt(128)
        const float4* row = (const float4*)(Wk2 + (size_t)tid * DD);
        float a = 0.f;
        #pragma unroll
        for (int k = 0; k < 32; ++k) {
            const float4 w = row[k];
            a += w.x * q2_l[4*k] + w.y * q2_l[4*k+1] + w.z * q2_l[4*k+2] + w.w * q2_l[4*k+3];
        }
        w2_ws[(size_t)b * DD + tid] = a * 0.08838834764831845f;  // 1/sqrt(128)
    }
}

// ---------------- k5: logits ----------------
__global__ __launch_bounds__(256)
void k5_logits(const float* __restrict__ node, const float* __restrict__ w2_ws,
               const void* __restrict__ maskp, float* __restrict__ out, int N)
{
    const int b = blockIdx.y, j = blockIdx.x, tid = threadIdx.x;
    const int rows = (N + NS - 1) / NS;
    const int n0 = j * rows;
    const int nend = min(n0 + rows, N);
    const bool m32 = detect_mask32(maskp);
    const int32_t* mi = (const int32_t*)maskp + (size_t)b * N;
    const uint8_t* mb = (const uint8_t*)maskp + (size_t)b * N;
    const int sub = tid & 7, rr = tid >> 3;

    const float4* wv = (const float4*)(w2_ws + (size_t)b * DD + sub * 16);
    const float4 w0 = wv[0], w1 = wv[1], w2v = wv[2], w3 = wv[3];
    const float* nodeB = node + (size_t)b * N * DD;
    float* outB = out + (size_t)b * N;

    for (int n = n0 + rr; n < nend; n += 32) {
        const float4* nr = (const float4*)(nodeB + (size_t)n * DD + sub * 16);
        const float4 a0 = nr[0], a1 = nr[1], a2 = nr[2], a3 = nr[3];
        float p = a0.x*w0.x + a0.y*w0.y + a0.z*w0.z + a0.w*w0.w
                + a1.x*w1.x + a1.y*w1.y + a1.z*w1.z + a1.w*w1.w
                + a2.x*w2v.x + a2.y*w2v.y + a2.z*w2v.z + a2.w*w2v.w
                + a3.x*w3.x + a3.y*w3.y + a3.z*w3.z + a3.w*w3.w;
        p += __shfl_xor(p, 1);
        p += __shfl_xor(p, 2);
        p += __shfl_xor(p, 4);
        if (sub == 0) {
            const bool m = m32 ? (mi[n] != 0) : (mb[n] != 0);
            const float t = 1.f - 2.f / (__expf(2.f * p) + 1.f);  // tanh
            outB[n] = m ? -1e9f : 10.f * t;
        }
    }
}

// ================ fallback: round-1 monolithic kernel ================
#define TPB 512
#define NMAX 1000
#define SPAD 9

__global__ __launch_bounds__(TPB)
void decoder_fallback(const float* __restrict__ node, const float* __restrict__ graph,
                      const float* __restrict__ ctx, const void* __restrict__ maskp,
                      const float* __restrict__ Wk1, const float* __restrict__ Wv,
                      const float* __restrict__ Wk2, const float* __restrict__ Wqf,
                      const float* __restrict__ Wout, const float* __restrict__ Wqs,
                      float* __restrict__ out, int N)
{
    __shared__ float node_tile[TILE * RP];
    __shared__ float scores[NMAX * SPAD];
    __shared__ float wq[NH * RP];
    __shared__ float s_lds[NH * RP];
    __shared__ float q1[DD];
    __shared__ float mha[DD];
    __shared__ float q2[DD];
    __shared__ float w2[DD];

    const int b = blockIdx.x, tid = threadIdx.x, lane = tid & 63, wave = tid >> 6;
    const bool mask32 = detect_mask32(maskp);
    const int32_t* mi = (const int32_t*)maskp + (size_t)b * N;
    const uint8_t* mb = (const uint8_t*)maskp + (size_t)b * N;
    const float* nodeB = node + (size_t)b * N * DD;

    if (tid < DD) {
        const float* ge = graph + (size_t)b * DD;
        const float* sc = ctx + (size_t)b * (DD + 2);
        float acc = 0.f;
        for (int k = 0; k < DD; ++k)     acc += ge[k] * Wqf[k * DD + tid];
        for (int k = 0; k < DD + 2; ++k) acc += sc[k] * Wqs[k * DD + tid];
        q1[tid] = acc;
    }
    __syncthreads();
    for (int idx = tid; idx < NH * DD; idx += TPB) {
        const int h = idx >> 7, dp = idx & (DD - 1);
        const float* wrow = Wk1 + dp * DD + h * DHD;
        float acc = 0.f;
        #pragma unroll
        for (int j = 0; j < DHD; ++j) acc += wrow[j] * q1[h * DHD + j];
        wq[h * RP + dp] = 0.25f * acc;
    }
    __syncthreads();
    const int ntiles = (N + TILE - 1) / TILE;
    const int n_local = tid >> 3, hA = tid & 7;
    for (int t = 0; t < ntiles; ++t) {
        const int n0 = t * TILE;
        #pragma unroll
        for (int c = 0; c < 4; ++c) {
            const int idx = c * (TPB * 4) + tid * 4;
            const int row = idx >> 7, col = idx & (DD - 1);
            if (n0 + row < N)
                *(float4*)&node_tile[row * RP + col] =
                    *(const float4*)(nodeB + (size_t)(n0 + row) * DD + col);
        }
        __syncthreads();
        if (n0 + n_local < N) {
            const float4* nr = (const float4*)&node_tile[n_local * RP];
            const float4* wr = (const float4*)&wq[hA * RP];
            float acc = 0.f;
            #pragma unroll
            for (int k = 0; k < DD / 4; ++k) {
                const float4 a = nr[k], w = wr[k];
                acc += a.x * w.x + a.y * w.y + a.z * w.z + a.w * w.w;
            }
            scores[(n0 + n_local) * SPAD + hA] = acc;
        }
        __syncthreads();
    }
    {
        const int h = wave;
        float sm[16];
        #pragma unroll
        for (int k = 0; k < 16; ++k) {
            const int n = lane + 64 * k;
            float v = -1e9f;
            if (n < N) {
                const bool m = mask32 ? (mi[n] != 0) : (mb[n] != 0);
                v = m ? -1e9f : scores[n * SPAD + h];
            }
            sm[k] = v;
        }
        float mx = sm[0];
        #pragma unroll
        for (int k = 1; k < 16; ++k) mx = fmaxf(mx, sm[k]);
        #pragma unroll
        for (int d = 1; d < 64; d <<= 1) mx = fmaxf(mx, __shfl_xor(mx, d));
        float e[16];
        float sum = 0.f;
        #pragma unroll
        for (int k = 0; k < 16; ++k) {
            const int n = lane + 64 * k;
            e[k] = (n < N) ? __expf(sm[k] - mx) : 0.f;
            sum += e[k];
        }
        #pragma unroll
        for (int d = 1; d < 64; d <<= 1) sum += __shfl_xor(sum, d);
        const float rinv = 1.f / sum;
        #pragma unroll
        for (int k = 0; k < 16; ++k) {
            const int n = lane + 64 * k;
            if (n < N) scores[n * SPAD + h] = e[k] * rinv;
        }
    }
    __syncthreads();
    {
        const int h = wave;
        const float2* n2 = (const float2*)nodeB;
        float a0 = 0.f, a1 = 0.f;
        #pragma unroll 4
        for (int n = 0; n < N; ++n) {
            const float at = scores[n * SPAD + h];
            const float2 v = n2[(size_t)n * 64 + lane];
            a0 += at * v.x;
            a1 += at * v.y;
        }
        s_lds[h * RP + 2 * lane] = a0;
        s_lds[h * RP + 2 * lane + 1] = a1;
    }
    __syncthreads();
    if (tid < DD) {
        const int h = tid >> 4;
        float acc = 0.f;
        for (int dp = 0; dp < DD; ++dp) acc += s_lds[h * RP + dp] * Wv[dp * DD + tid];
        mha[tid] = acc;
    }
    __syncthreads();
    if (tid < DD) {
        float acc = 0.f;
        for (int e = 0; e < DD; ++e) acc += mha[e] * Wout[e * DD + tid];
        q2[tid] = acc;
    }
    __syncthreads();
    if (tid < DD) {
        const float4* row = (const float4*)(Wk2 + tid * DD);
        float acc = 0.f;
        #pragma unroll
        for (int k = 0; k < DD / 4; ++k) {
            const float4 wv = row[k];
            acc += wv.x * q2[4*k] + wv.y * q2[4*k+1] + wv.z * q2[4*k+2] + wv.w * q2[4*k+3];
        }
        w2[tid] = acc * 0.08838834764831845f;
    }
    __syncthreads();
    {
        const float wa = w2[2 * lane], wb = w2[2 * lane + 1];
        const float2* n2 = (const float2*)nodeB;
        float* outB = out + (size_t)b * N;
        for (int n = wave; n < N; n += NH) {
            const float2 v = n2[(size_t)n * 64 + lane];
            float p = v.x * wa + v.y * wb;
            #pragma unroll
            for (int d = 1; d < 64; d <<= 1) p += __shfl_xor(p, d);
            if (lane == 0) {
                const bool m = mask32 ? (mi[n] != 0) : (mb[n] != 0);
                const float t = 1.f - 2.f / (__expf(2.f * p) + 1.f);
                outB[n] = m ? -1e9f : 10.f * t;
            }
        }
    }
}

extern "C" void kernel_launch(void* const* d_in, const int* in_sizes, int n_in,
                              void* d_out, int out_size, void* d_ws, size_t ws_size,
                              hipStream_t stream) {
    (void)n_in; (void)out_size;
    const float* node  = (const float*)d_in[0];
    const float* graph = (const float*)d_in[1];
    const float* ctx   = (const float*)d_in[2];
    const void*  mask  = d_in[3];
    const float* Wk1   = (const float*)d_in[4];
    const float* Wv    = (const float*)d_in[5];
    const float* Wk2   = (const float*)d_in[6];
    const float* Wqf   = (const float*)d_in[7];
    const float* Wout  = (const float*)d_in[8];
    const float* Wqs   = (const float*)d_in[9];

    const int B = in_sizes[1] / DD;
    const int N = in_sizes[0] / (B * DD);

    // workspace layout (floats)
    const size_t off_wq    = 0;
    const size_t off_spart = off_wq + (size_t)B * NH * DD;
    const size_t off_mz    = off_spart + (size_t)B * NS * NH * DD;
    const size_t off_w2    = off_mz + (size_t)B * NS * NH * 2;
    const size_t need_f    = off_w2 + (size_t)B * DD;

    if (N <= NMAX_PAD && ws_size >= need_f * sizeof(float)) {
        float* ws       = (float*)d_ws;
        float* wq_ws    = ws + off_wq;
        float* spart_ws = ws + off_spart;
        float* mz_ws    = ws + off_mz;
        float* w2_ws    = ws + off_w2;

        k0_prep<<<B, 128, 0, stream>>>(graph, ctx, Wk1, Wqf, Wqs, wq_ws);
        kA_flash<<<dim3(NS, B), 512, 0, stream>>>(node, wq_ws, mask, spart_ws, mz_ws, N);
        kB_combine<<<B, 128, 0, stream>>>(spart_ws, mz_ws, Wv, Wout, Wk2, w2_ws);
        k5_logits<<<dim3(NS, B), 256, 0, stream>>>(node, w2_ws, mask, (float*)d_out, N);
    } else {
        decoder_fallback<<<B, TPB, 0, stream>>>(node, graph, ctx, mask,
                                                Wk1, Wv, Wk2, Wqf, Wout, Wqs,
                                                (float*)d_out, N);
    }
}

// Round 4
// 97.453 us; speedup vs baseline: 1.2166x; 1.2166x over previous
//
#include <hip/hip_runtime.h>
#include <stdint.h>

// DecoderCell, folded algebra + bf16-MFMA flash attention.
//   k0: wq[b,h,:] = 0.25 * Wk1[:,h*16:+16] @ (graph@Wqf + ctx@Wqs)[h]
//   kA: per (b, N-slice<=128 rows): scores^T = wq(A-frags, regs) x node(LDS bf16)
//       via mfma_16x16x32_bf16; softmax (shuffle); P@node via MFMA -> spart, (m,z)
//   kB: combine slice partials -> s[h,:]; mha -> q2 -> w2=(Wk2@q2)/sqrt(128)
//   k5: logit[b,n] = mask ? -1e9 : 10*tanh(node[b,n,:] . w2)   (L3-served pass)

#define DD 128
#define NH 8
#define DHD 16
#define NS 8
#define TILE 64
#define RP 132
#define SP 9
#define NMAX_PAD 1024

typedef short v8s __attribute__((ext_vector_type(8)));
typedef float v4f __attribute__((ext_vector_type(4)));

__device__ __forceinline__ unsigned short f2bf(float x) {
    unsigned u = __float_as_uint(x);
    u += 0x7fffu + ((u >> 16) & 1u);   // RNE
    return (unsigned short)(u >> 16);
}

__device__ __forceinline__ bool detect_mask32(const void* maskp) {
    // int32 0/1 mask -> first 16 words all <=1; packed bool8 -> astronomically unlikely
    const uint32_t* mw = (const uint32_t*)maskp;
    bool m32 = true;
    #pragma unroll
    for (int i = 0; i < 16; ++i) m32 = m32 && (mw[i] <= 1u);
    return m32;
}

// ---------------- k0: per-head folded query ----------------
__global__ __launch_bounds__(128)
void k0_prep(const float* __restrict__ graph, const float* __restrict__ ctx,
             const float* __restrict__ Wk1, const float* __restrict__ Wqf,
             const float* __restrict__ Wqs, float* __restrict__ wq_ws)
{
    __shared__ float q1[DD];
    const int b = blockIdx.x, tid = threadIdx.x;
    const float* ge = graph + (size_t)b * DD;
    const float* sc = ctx + (size_t)b * (DD + 2);
    float acc = 0.f;
    #pragma unroll 4
    for (int k = 0; k < DD; ++k)     acc += ge[k] * Wqf[k * DD + tid];
    #pragma unroll 4
    for (int k = 0; k < DD + 2; ++k) acc += sc[k] * Wqs[k * DD + tid];
    q1[tid] = acc;
    __syncthreads();
    const float* wrow = Wk1 + (size_t)tid * DD;   // row dp = tid
    #pragma unroll
    for (int h = 0; h < NH; ++h) {
        float a = 0.f;
        #pragma unroll
        for (int j = 0; j < DHD; ++j) a += wrow[h * DHD + j] * q1[h * DHD + j];
        wq_ws[(size_t)b * NH * DD + h * DD + tid] = 0.25f * a;  // 1/sqrt(16)
    }
}

// ---------------- kA: MFMA flash over one <=128-row slice ----------------
// Layouts (mfma_f32_16x16x32_bf16, 64-lane wave, c=lane&15, g=lane>>4):
//   A[m][k]: m=c, k=g*8+i     B[k][n]: k=g*8+i, n=c     C[m][n]: m=g*4+r, n=c
__global__ __launch_bounds__(512)
void kA_mfma(const float* __restrict__ node, const float* __restrict__ wq_ws,
             const void* __restrict__ maskp, float* __restrict__ spart_ws,
             float* __restrict__ mz_ws, int N)
{
    __shared__ __align__(16) unsigned short tA[2][8][64][16]; // 2 tiles, col-subtiled bf16, 32 KB
    __shared__ __align__(16) unsigned short Ph[2][16][72];    // P^T as [head][row], padded, 4.5 KB
    __shared__ float wmax[16][9];
    __shared__ float zpart[16][9];
    __shared__ float mfin[16];

    const int b = blockIdx.y, j = blockIdx.x, tid = threadIdx.x;
    const int lane = tid & 63, w = tid >> 6;
    const int c = lane & 15, g = lane >> 4;
    const int rows = (N + NS - 1) / NS;
    const int n0 = j * rows;
    const int nend = min(n0 + rows, N);

    // empty slice (only when N < NS): zero partials, sentinel m
    if (nend <= n0) {
        float* sp = spart_ws + ((size_t)b * NS + j) * NH * DD;
        for (int o = tid; o < NH * DD; o += 512) sp[o] = 0.f;
        if (tid < NH) {
            float* mzp = mz_ws + (((size_t)b * NS + j) * NH + tid) * 2;
            mzp[0] = -1e30f; mzp[1] = 0.f;
        }
        return;
    }

    const bool m32 = detect_mask32(maskp);
    const int32_t* mi = (const int32_t*)maskp + (size_t)b * N;
    const uint8_t* mb = (const uint8_t*)maskp + (size_t)b * N;
    const float* nodeB = node + (size_t)b * N * DD;

    // ---- wq A-fragments (held in registers; heads 8..15 zero-padded)
    v8s aw[4];
    #pragma unroll
    for (int kk = 0; kk < 4; ++kk) {
        v8s a;
        #pragma unroll
        for (int i = 0; i < 8; ++i) a[i] = 0;
        if (c < NH) {
            const float* wr = wq_ws + (size_t)b * NH * DD + (size_t)c * DD + kk * 32 + g * 8;
            #pragma unroll
            for (int i = 0; i < 8; ++i) a[i] = (short)f2bf(wr[i]);
        }
        aw[kk] = a;
    }

    // ---- stage 2x(64x128) node tile as bf16, col-subtiled [chunk][row][16]
    {
        const int L = tid >> 3, c8 = tid & 7;
        #pragma unroll
        for (int t = 0; t < 2; ++t) {
            const int n = n0 + t * 64 + L;
            unsigned short tmp[16];
            if (n < nend) {
                const float4* src = (const float4*)(nodeB + (size_t)n * DD + c8 * 16);
                #pragma unroll
                for (int k = 0; k < 4; ++k) {
                    const float4 v = src[k];
                    tmp[4*k+0] = f2bf(v.x); tmp[4*k+1] = f2bf(v.y);
                    tmp[4*k+2] = f2bf(v.z); tmp[4*k+3] = f2bf(v.w);
                }
            } else {
                #pragma unroll
                for (int k = 0; k < 16; ++k) tmp[k] = 0;
            }
            *(v8s*)&tA[t][c8][L][0] = *(v8s*)&tmp[0];
            *(v8s*)&tA[t][c8][L][8] = *(v8s*)&tmp[8];
        }
    }
    __syncthreads();

    // ---- scores^T: wave (ts,rg) computes C[head 0..15][rows rg*16..+15] of tile ts
    const int ts = w >> 2, rg = w & 3;
    const int nrow = n0 + ts * 64 + rg * 16 + c;   // this lane's score row
    v4f sc = {0.f, 0.f, 0.f, 0.f};
    #pragma unroll
    for (int kk = 0; kk < 4; ++kk) {
        const v8s bfrag = *(const v8s*)&tA[ts][kk * 2 + (g >> 1)][rg * 16 + c][(g & 1) * 8];
        sc = __builtin_amdgcn_mfma_f32_16x16x32_bf16(aw[kk], bfrag, sc, 0, 0, 0);
    }

    // ---- mask / pad sentinels (per row = per lane)
    float s4[4];
    {
        const bool valid = nrow < nend;
        const bool msk = valid && (m32 ? (mi[nrow] != 0) : (mb[nrow] != 0));
        #pragma unroll
        for (int r = 0; r < 4; ++r)
            s4[r] = !valid ? -1e30f : (msk ? -1e9f : sc[r]);
    }

    // ---- per-wave max over its 16 rows, then block max per head
    {
        float mx[4];
        #pragma unroll
        for (int r = 0; r < 4; ++r) mx[r] = s4[r];
        #pragma unroll
        for (int d = 1; d < 16; d <<= 1) {
            #pragma unroll
            for (int r = 0; r < 4; ++r) mx[r] = fmaxf(mx[r], __shfl_xor(mx[r], d));
        }
        if (c == 0) {
            #pragma unroll
            for (int r = 0; r < 4; ++r) wmax[g * 4 + r][w] = mx[r];
        }
    }
    __syncthreads();
    if (w == 0 && lane < 16) {
        float m = wmax[lane][0];
        #pragma unroll
        for (int ww = 1; ww < 8; ++ww) m = fmaxf(m, wmax[lane][ww]);
        mfin[lane] = m;
    }
    __syncthreads();

    // ---- e = exp(s - m); z partial; write P^T bf16 [head][row]
    {
        float e4[4];
        #pragma unroll
        for (int r = 0; r < 4; ++r) e4[r] = __expf(s4[r] - mfin[g * 4 + r]);
        float zr[4];
        #pragma unroll
        for (int r = 0; r < 4; ++r) zr[r] = e4[r];
        #pragma unroll
        for (int d = 1; d < 16; d <<= 1) {
            #pragma unroll
            for (int r = 0; r < 4; ++r) zr[r] += __shfl_xor(zr[r], d);
        }
        if (c == 0) {
            #pragma unroll
            for (int r = 0; r < 4; ++r) zpart[g * 4 + r][w] = zr[r];
        }
        #pragma unroll
        for (int r = 0; r < 4; ++r)
            Ph[ts][g * 4 + r][rg * 16 + c] = f2bf(e4[r]);
    }
    __syncthreads();

    // ---- P @ node: wave w owns 16-col tile w; K = 128 rows (both tiles)
    v4f c2 = {0.f, 0.f, 0.f, 0.f};
    #pragma unroll
    for (int s = 0; s < 4; ++s) {
        const int t2 = s >> 1, s1 = s & 1;
        const v8s pa = *(const v8s*)&Ph[t2][c][s1 * 32 + g * 8];
        v8s bb;
        #pragma unroll
        for (int i = 0; i < 8; ++i)
            bb[i] = (short)tA[t2][w][s1 * 32 + g * 8 + i][c];
        c2 = __builtin_amdgcn_mfma_f32_16x16x32_bf16(pa, bb, c2, 0, 0, 0);
    }

    // ---- outputs
    if (g < 2) {   // heads 0..7 live in m = g*4+r < 8
        float* sp = spart_ws + ((size_t)b * NS + j) * NH * DD;
        #pragma unroll
        for (int r = 0; r < 4; ++r)
            sp[(g * 4 + r) * DD + w * 16 + c] = c2[r];
    }
    if (w == 0 && lane < NH) {
        float z = 0.f;
        #pragma unroll
        for (int ww = 0; ww < 8; ++ww) z += zpart[lane][ww];
        float* mzp = mz_ws + (((size_t)b * NS + j) * NH + lane) * 2;
        mzp[0] = mfin[lane];
        mzp[1] = z;
    }
}

// ---------------- kB: combine partials + mha + q2 + w2 ----------------
__global__ __launch_bounds__(128)
void kB_combine(const float* __restrict__ spart_ws, const float* __restrict__ mz_ws,
                const float* __restrict__ Wv, const float* __restrict__ Wout,
                const float* __restrict__ Wk2, float* __restrict__ w2_ws)
{
    __shared__ float m_l[NH * NS], z_l[NH * NS], wt[NH * NS];
    __shared__ float s_l[NH * DD];
    __shared__ float mha_l[DD];
    __shared__ float q2_l[DD];
    const int b = blockIdx.x, tid = threadIdx.x;

    if (tid < NH * NS) {
        const int h = tid >> 3, j = tid & 7;
        const float* mzp = mz_ws + (((size_t)b * NS + j) * NH + h) * 2;
        m_l[h * NS + j] = mzp[0];
        z_l[h * NS + j] = mzp[1];
    }
    __syncthreads();
    if (tid < NH) {
        const int h = tid;
        float M = -1e30f;
        #pragma unroll
        for (int j = 0; j < NS; ++j) M = fmaxf(M, m_l[h * NS + j]);
        float w[NS], Z = 0.f;
        #pragma unroll
        for (int j = 0; j < NS; ++j) {
            w[j] = __expf(m_l[h * NS + j] - M);
            Z += z_l[h * NS + j] * w[j];
        }
        const float rz = 1.f / Z;
        #pragma unroll
        for (int j = 0; j < NS; ++j) wt[h * NS + j] = w[j] * rz;
    }
    __syncthreads();
    const float* sp = spart_ws + (size_t)b * NS * NH * DD;
    for (int o = tid; o < NH * DD; o += 128) {
        const int h = o >> 7;
        float s = 0.f;
        #pragma unroll
        for (int j = 0; j < NS; ++j)
            s += sp[(size_t)j * NH * DD + o] * wt[h * NS + j];
        s_l[o] = s;
    }
    __syncthreads();
    {   // mha[e] = s[h(e)] . Wv[:,e]
        const int h = tid >> 4;
        float a = 0.f;
        for (int dp = 0; dp < DD; ++dp) a += s_l[h * DD + dp] * Wv[dp * DD + tid];
        mha_l[tid] = a;
    }
    __syncthreads();
    {   // q2 = mha @ Wout
        float a = 0.f;
        for (int e = 0; e < DD; ++e) a += mha_l[e] * Wout[e * DD + tid];
        q2_l[tid] = a;
    }
    __syncthreads();
    {   // w2 = (Wk2 @ q2) / sqrt(128)
        const float4* row = (const float4*)(Wk2 + (size_t)tid * DD);
        float a = 0.f;
        #pragma unroll
        for (int k = 0; k < 32; ++k) {
            const float4 w = row[k];
            a += w.x * q2_l[4*k] + w.y * q2_l[4*k+1] + w.z * q2_l[4*k+2] + w.w * q2_l[4*k+3];
        }
        w2_ws[(size_t)b * DD + tid] = a * 0.08838834764831845f;  // 1/sqrt(128)
    }
}

// ---------------- k5: logits ----------------
__global__ __launch_bounds__(256)
void k5_logits(const float* __restrict__ node, const float* __restrict__ w2_ws,
               const void* __restrict__ maskp, float* __restrict__ out, int N)
{
    const int b = blockIdx.y, j = blockIdx.x, tid = threadIdx.x;
    const int rows = (N + NS - 1) / NS;
    const int n0 = j * rows;
    const int nend = min(n0 + rows, N);
    const bool m32 = detect_mask32(maskp);
    const int32_t* mi = (const int32_t*)maskp + (size_t)b * N;
    const uint8_t* mb = (const uint8_t*)maskp + (size_t)b * N;
    const int sub = tid & 7, rr = tid >> 3;

    const float4* wv = (const float4*)(w2_ws + (size_t)b * DD + sub * 16);
    const float4 w0 = wv[0], w1 = wv[1], w2v = wv[2], w3 = wv[3];
    const float* nodeB = node + (size_t)b * N * DD;
    float* outB = out + (size_t)b * N;

    for (int n = n0 + rr; n < nend; n += 32) {
        const float4* nr = (const float4*)(nodeB + (size_t)n * DD + sub * 16);
        const float4 a0 = nr[0], a1 = nr[1], a2 = nr[2], a3 = nr[3];
        float p = a0.x*w0.x + a0.y*w0.y + a0.z*w0.z + a0.w*w0.w
                + a1.x*w1.x + a1.y*w1.y + a1.z*w1.z + a1.w*w1.w
                + a2.x*w2v.x + a2.y*w2v.y + a2.z*w2v.z + a2.w*w2v.w
                + a3.x*w3.x + a3.y*w3.y + a3.z*w3.z + a3.w*w3.w;
        p += __shfl_xor(p, 1);
        p += __shfl_xor(p, 2);
        p += __shfl_xor(p, 4);
        if (sub == 0) {
            const bool m = m32 ? (mi[n] != 0) : (mb[n] != 0);
            const float t = 1.f - 2.f / (__expf(2.f * p) + 1.f);  // tanh
            outB[n] = m ? -1e9f : 10.f * t;
        }
    }
}

// ================ fallback: round-1 monolithic kernel ================
#define TPB 512
#define NMAX 1000
#define SPAD 9

__global__ __launch_bounds__(TPB)
void decoder_fallback(const float* __restrict__ node, const float* __restrict__ graph,
                      const float* __restrict__ ctx, const void* __restrict__ maskp,
                      const float* __restrict__ Wk1, const float* __restrict__ Wv,
                      const float* __restrict__ Wk2, const float* __restrict__ Wqf,
                      const float* __restrict__ Wout, const float* __restrict__ Wqs,
                      float* __restrict__ out, int N)
{
    __shared__ float node_tile[TILE * RP];
    __shared__ float scores[NMAX * SPAD];
    __shared__ float wq[NH * RP];
    __shared__ float s_lds[NH * RP];
    __shared__ float q1[DD];
    __shared__ float mha[DD];
    __shared__ float q2[DD];
    __shared__ float w2[DD];

    const int b = blockIdx.x, tid = threadIdx.x, lane = tid & 63, wave = tid >> 6;
    const bool mask32 = detect_mask32(maskp);
    const int32_t* mi = (const int32_t*)maskp + (size_t)b * N;
    const uint8_t* mb = (const uint8_t*)maskp + (size_t)b * N;
    const float* nodeB = node + (size_t)b * N * DD;

    if (tid < DD) {
        const float* ge = graph + (size_t)b * DD;
        const float* sc = ctx + (size_t)b * (DD + 2);
        float acc = 0.f;
        for (int k = 0; k < DD; ++k)     acc += ge[k] * Wqf[k * DD + tid];
        for (int k = 0; k < DD + 2; ++k) acc += sc[k] * Wqs[k * DD + tid];
        q1[tid] = acc;
    }
    __syncthreads();
    for (int idx = tid; idx < NH * DD; idx += TPB) {
        const int h = idx >> 7, dp = idx & (DD - 1);
        const float* wrow = Wk1 + dp * DD + h * DHD;
        float acc = 0.f;
        #pragma unroll
        for (int j = 0; j < DHD; ++j) acc += wrow[j] * q1[h * DHD + j];
        wq[h * RP + dp] = 0.25f * acc;
    }
    __syncthreads();
    const int ntiles = (N + TILE - 1) / TILE;
    const int n_local = tid >> 3, hA = tid & 7;
    for (int t = 0; t < ntiles; ++t) {
        const int n0 = t * TILE;
        #pragma unroll
        for (int cc = 0; cc < 4; ++cc) {
            const int idx = cc * (TPB * 4) + tid * 4;
            const int row = idx >> 7, col = idx & (DD - 1);
            if (n0 + row < N)
                *(float4*)&node_tile[row * RP + col] =
                    *(const float4*)(nodeB + (size_t)(n0 + row) * DD + col);
        }
        __syncthreads();
        if (n0 + n_local < N) {
            const float4* nr = (const float4*)&node_tile[n_local * RP];
            const float4* wr = (const float4*)&wq[hA * RP];
            float acc = 0.f;
            #pragma unroll
            for (int k = 0; k < DD / 4; ++k) {
                const float4 a = nr[k], wv = wr[k];
                acc += a.x * wv.x + a.y * wv.y + a.z * wv.z + a.w * wv.w;
            }
            scores[(n0 + n_local) * SPAD + hA] = acc;
        }
        __syncthreads();
    }
    {
        const int h = wave;
        float sm[16];
        #pragma unroll
        for (int k = 0; k < 16; ++k) {
            const int n = lane + 64 * k;
            float v = -1e9f;
            if (n < N) {
                const bool m = mask32 ? (mi[n] != 0) : (mb[n] != 0);
                v = m ? -1e9f : scores[n * SPAD + h];
            }
            sm[k] = v;
        }
        float mx = sm[0];
        #pragma unroll
        for (int k = 1; k < 16; ++k) mx = fmaxf(mx, sm[k]);
        #pragma unroll
        for (int d = 1; d < 64; d <<= 1) mx = fmaxf(mx, __shfl_xor(mx, d));
        float e[16];
        float sum = 0.f;
        #pragma unroll
        for (int k = 0; k < 16; ++k) {
            const int n = lane + 64 * k;
            e[k] = (n < N) ? __expf(sm[k] - mx) : 0.f;
            sum += e[k];
        }
        #pragma unroll
        for (int d = 1; d < 64; d <<= 1) sum += __shfl_xor(sum, d);
        const float rinv = 1.f / sum;
        #pragma unroll
        for (int k = 0; k < 16; ++k) {
            const int n = lane + 64 * k;
            if (n < N) scores[n * SPAD + h] = e[k] * rinv;
        }
    }
    __syncthreads();
    {
        const int h = wave;
        const float2* n2 = (const float2*)nodeB;
        float a0 = 0.f, a1 = 0.f;
        #pragma unroll 4
        for (int n = 0; n < N; ++n) {
            const float at = scores[n * SPAD + h];
            const float2 v = n2[(size_t)n * 64 + lane];
            a0 += at * v.x;
            a1 += at * v.y;
        }
        s_lds[h * RP + 2 * lane] = a0;
        s_lds[h * RP + 2 * lane + 1] = a1;
    }
    __syncthreads();
    if (tid < DD) {
        const int h = tid >> 4;
        float acc = 0.f;
        for (int dp = 0; dp < DD; ++dp) acc += s_lds[h * RP + dp] * Wv[dp * DD + tid];
        mha[tid] = acc;
    }
    __syncthreads();
    if (tid < DD) {
        float acc = 0.f;
        for (int e = 0; e < DD; ++e) acc += mha[e] * Wout[e * DD + tid];
        q2[tid] = acc;
    }
    __syncthreads();
    if (tid < DD) {
        const float4* row = (const float4*)(Wk2 + tid * DD);
        float acc = 0.f;
        #pragma unroll
        for (int k = 0; k < DD / 4; ++k) {
            const float4 wv = row[k];
            acc += wv.x * q2[4*k] + wv.y * q2[4*k+1] + wv.z * q2[4*k+2] + wv.w * q2[4*k+3];
        }
        w2[tid] = acc * 0.08838834764831845f;
    }
    __syncthreads();
    {
        const float wa = w2[2 * lane], wb = w2[2 * lane + 1];
        const float2* n2 = (const float2*)nodeB;
        float* outB = out + (size_t)b * N;
        for (int n = wave; n < N; n += NH) {
            const float2 v = n2[(size_t)n * 64 + lane];
            float p = v.x * wa + v.y * wb;
            #pragma unroll
            for (int d = 1; d < 64; d <<= 1) p += __shfl_xor(p, d);
            if (lane == 0) {
                const bool m = mask32 ? (mi[n] != 0) : (mb[n] != 0);
                const float t = 1.f - 2.f / (__expf(2.f * p) + 1.f);
                outB[n] = m ? -1e9f : 10.f * t;
            }
        }
    }
}

extern "C" void kernel_launch(void* const* d_in, const int* in_sizes, int n_in,
                              void* d_out, int out_size, void* d_ws, size_t ws_size,
                              hipStream_t stream) {
    (void)n_in; (void)out_size;
    const float* node  = (const float*)d_in[0];
    const float* graph = (const float*)d_in[1];
    const float* ctx   = (const float*)d_in[2];
    const void*  mask  = d_in[3];
    const float* Wk1   = (const float*)d_in[4];
    const float* Wv    = (const float*)d_in[5];
    const float* Wk2   = (const float*)d_in[6];
    const float* Wqf   = (const float*)d_in[7];
    const float* Wout  = (const float*)d_in[8];
    const float* Wqs   = (const float*)d_in[9];

    const int B = in_sizes[1] / DD;
    const int N = in_sizes[0] / (B * DD);

    // workspace layout (floats)
    const size_t off_wq    = 0;
    const size_t off_spart = off_wq + (size_t)B * NH * DD;
    const size_t off_mz    = off_spart + (size_t)B * NS * NH * DD;
    const size_t off_w2    = off_mz + (size_t)B * NS * NH * 2;
    const size_t need_f    = off_w2 + (size_t)B * DD;

    if (N <= NMAX_PAD && ws_size >= need_f * sizeof(float)) {
        float* ws       = (float*)d_ws;
        float* wq_ws    = ws + off_wq;
        float* spart_ws = ws + off_spart;
        float* mz_ws    = ws + off_mz;
        float* w2_ws    = ws + off_w2;

        k0_prep<<<B, 128, 0, stream>>>(graph, ctx, Wk1, Wqf, Wqs, wq_ws);
        kA_mfma<<<dim3(NS, B), 512, 0, stream>>>(node, wq_ws, mask, spart_ws, mz_ws, N);
        kB_combine<<<B, 128, 0, stream>>>(spart_ws, mz_ws, Wv, Wout, Wk2, w2_ws);
        k5_logits<<<dim3(NS, B), 256, 0, stream>>>(node, w2_ws, mask, (float*)d_out, N);
    } else {
        decoder_fallback<<<B, TPB, 0, stream>>>(node, graph, ctx, mask,
                                                Wk1, Wv, Wk2, Wqf, Wout, Wqs,
                                                (float*)d_out, N);
    }
}